// Round 2
// baseline (4204.500 us; speedup 1.0000x reference)
//
#include <hip/hip_runtime.h>
#include <math.h>

#define B_ROWS 262144
#define NVB 256
#define VBS_C 1024
#define GAMMA_C 1.3f
#define EPS_C 1e-5f
#define SQH_C 0.70710678118654752440f
#define SL_SCALE (1.0f/201326592.0f)   // 1/(3*B*256)

typedef _Float16 f16;
typedef f16 f16x8 __attribute__((ext_vector_type(8)));
typedef f16 f16x4 __attribute__((ext_vector_type(4)));
typedef float f32x4 __attribute__((ext_vector_type(4)));

// XOR swizzle within a 128B row: spreads the 16-lane column-slice reads across banks (guide G4)
static __device__ __forceinline__ unsigned swz(int row, int kbyte) {
  return (unsigned)((row * 128 + kbyte) ^ ((row & 7) << 4));
}

// ---------------- bn0: full-batch stats ----------------
__global__ void bn0_accum(const float* __restrict__ x, float* __restrict__ sums) {
  const int col = threadIdx.x;                 // 256 threads = 256 features
  const size_t r0 = (size_t)blockIdx.x * 128;  // 2048 blocks * 128 rows
  float s1 = 0.f, s2 = 0.f;
  for (int i = 0; i < 128; ++i) {
    float v = x[(r0 + i) * 256 + col];
    s1 += v; s2 += v * v;
  }
  atomicAdd(&sums[col * 2], s1);
  atomicAdd(&sums[col * 2 + 1], s2);
}

__global__ void bn0_final(const float* __restrict__ sums, const float* __restrict__ g,
                          const float* __restrict__ b, float* __restrict__ bnA,
                          float* __restrict__ bnB) {
  int c = threadIdx.x;
  float mu = sums[c * 2] * (1.f / B_ROWS);
  float var = sums[c * 2 + 1] * (1.f / B_ROWS) - mu * mu;
  float a = rsqrtf(var + EPS_C) * g[c];
  bnA[c] = a;
  bnB[c] = b[c] - mu * a;
}

// ---------------- weight prep: f32 [K][256] -> f16 [256][K] ----------------
__global__ void wprep(const float* __restrict__ src, f16* __restrict__ dst, int K) {
  int idx = blockIdx.x * 256 + threadIdx.x;    // grid = K blocks -> exactly 256*K threads
  int n = idx / K, k = idx - n * K;
  dst[idx] = (f16)src[(size_t)k * 256 + n];
}

// ---------------- GEMM: [B x K] @ [K x 256] -> pre (f32) + per-VB column stats ----------------
// AMODE 0: A is f16 with leading dim lda. AMODE 1: A[r][k] = (x[r][k]*bnA[k]+bnB[k]) * M[r][k]
template <int KDIM, int AMODE>
__launch_bounds__(256)
__global__ void gemm_k(const f16* __restrict__ A, int lda,
                       const float* __restrict__ Mm, const float* __restrict__ xg,
                       const float* __restrict__ bnA, const float* __restrict__ bnB,
                       const f16* __restrict__ Wt,   // [256][KDIM] f16 (n-major, k contig)
                       float* __restrict__ pre, float* __restrict__ vbstats) {
  __shared__ f16 sW[256 * 64];
  __shared__ f16 sA[64 * 64];
  __shared__ float sBn[512];
  char* sWc = (char*)sW;
  char* sAc = (char*)sA;
  const int tid = threadIdx.x;
  const int row0 = blockIdx.x << 6;  // 64 rows per WG
  const int vb = row0 >> 10;
  if (AMODE == 1) {
    sBn[tid] = bnA[tid];
    sBn[256 + tid] = bnB[tid];
  }
  f32x4 zero = {0.f, 0.f, 0.f, 0.f};
  f32x4 acc[4][4];
#pragma unroll
  for (int i = 0; i < 4; ++i)
#pragma unroll
    for (int j = 0; j < 4; ++j) acc[i][j] = zero;
  const int wv = tid >> 6;
  const int ln = tid & 63;
  const int g = ln >> 4, c = ln & 15;
  if (AMODE == 1) __syncthreads();

  for (int kt = 0; kt < KDIM / 64; ++kt) {
    // stage W tile: 256 n x 64 k (fully coalesced 16B chunks)
#pragma unroll
    for (int it = 0; it < 8; ++it) {
      int flat = (it << 8) + tid;
      int n = flat >> 3, kc = flat & 7;
      f16x8 v = *(const f16x8*)(Wt + n * KDIM + kt * 64 + kc * 8);
      *(f16x8*)(sWc + swz(n, kc * 16)) = v;
    }
    // stage A tile: 64 rows x 64 k
#pragma unroll
    for (int it = 0; it < 2; ++it) {
      int flat = (it << 8) + tid;
      int r = flat >> 3, kc = flat & 7;
      f16x8 v;
      if (AMODE == 0) {
        v = *(const f16x8*)(A + (size_t)(row0 + r) * lda + kt * 64 + kc * 8);
      } else {
        int k0 = kt * 64 + kc * 8;
        const float* xr = xg + (size_t)(row0 + r) * 256 + k0;
        const float* mr = Mm + (size_t)(row0 + r) * 256 + k0;  // masks base is 4B-aligned only
        f32x4 x0 = *(const f32x4*)(xr);
        f32x4 x1 = *(const f32x4*)(xr + 4);
#pragma unroll
        for (int j = 0; j < 4; ++j) {
          v[j]     = (f16)((x0[j] * sBn[k0 + j]     + sBn[256 + k0 + j])     * mr[j]);
          v[4 + j] = (f16)((x1[j] * sBn[k0 + 4 + j] + sBn[256 + k0 + 4 + j]) * mr[4 + j]);
        }
      }
      *(f16x8*)(sAc + swz(r, kc * 16)) = v;
    }
    __syncthreads();
#pragma unroll
    for (int ks = 0; ks < 2; ++ks) {
      f16x8 af[4], bfr[4];
#pragma unroll
      for (int mt = 0; mt < 4; ++mt) {
        int rr = (mt << 4) + c;
        af[mt] = *(const f16x8*)(sAc + swz(rr, ks * 64 + g * 16));
      }
#pragma unroll
      for (int nt = 0; nt < 4; ++nt) {
        int nn = (wv << 6) + (nt << 4) + c;
        bfr[nt] = *(const f16x8*)(sWc + swz(nn, ks * 64 + g * 16));
      }
#pragma unroll
      for (int mt = 0; mt < 4; ++mt)
#pragma unroll
        for (int nt = 0; nt < 4; ++nt)
          acc[mt][nt] = __builtin_amdgcn_mfma_f32_16x16x32_f16(af[mt], bfr[nt], acc[mt][nt], 0, 0, 0);
    }
    __syncthreads();
  }

  // epilogue: store f32 pre + exact f32 column stats (sum, sumsq) per VB
#pragma unroll
  for (int nt = 0; nt < 4; ++nt) {
    float s1 = 0.f, s2 = 0.f;
    const int col = (wv << 6) + (nt << 4) + c;
#pragma unroll
    for (int mt = 0; mt < 4; ++mt) {
#pragma unroll
      for (int j = 0; j < 4; ++j) {
        float vv = acc[mt][nt][j];
        s1 += vv; s2 += vv * vv;
        pre[(size_t)(row0 + (mt << 4) + (g << 2) + j) * 256 + col] = vv;
      }
    }
    s1 += __shfl_xor(s1, 16); s2 += __shfl_xor(s2, 16);
    s1 += __shfl_xor(s1, 32); s2 += __shfl_xor(s2, 32);
    if (g == 0) {
      atomicAdd(&vbstats[((vb << 8) + col) * 2 + 0], s1);
      atomicAdd(&vbstats[((vb << 8) + col) * 2 + 1], s2);
    }
  }
}

// ---------------- BN + GLU (+ residual, + d_out epilogue) ----------------
// VARIANT 0: h = glu(pre);  1: h = (hp + glu(pre))*sqrt(.5);  2: variant1 + dout += relu(h[:,:64])
template <int VARIANT>
__launch_bounds__(256)
__global__ void glu_k(const float* __restrict__ pre, const float* __restrict__ vbstats,
                      const float* __restrict__ gv, const float* __restrict__ bv,
                      const f16* __restrict__ hp, f16* __restrict__ ho,
                      float* __restrict__ dout, int first) {
  __shared__ float sA[256], sB[256];
  const int tid = threadIdx.x;
  const int row0 = blockIdx.x << 4;  // 16 rows per WG (all in same VB)
  const int vb = row0 >> 10;
  {
    float s1 = vbstats[((vb << 8) + tid) * 2];
    float s2 = vbstats[((vb << 8) + tid) * 2 + 1];
    float mu = s1 * (1.f / VBS_C);
    float var = s2 * (1.f / VBS_C) - mu * mu;
    float a = rsqrtf(var + EPS_C) * gv[tid];
    sA[tid] = a;
    sB[tid] = bv[tid] - mu * a;
  }
  __syncthreads();
  const int r = row0 + (tid >> 4);
  const int cb = (tid & 15) << 3;
  const float* p1 = pre + (size_t)r * 256 + cb;
  f32x4 a0 = *(const f32x4*)(p1);
  f32x4 a1 = *(const f32x4*)(p1 + 4);
  f32x4 b0 = *(const f32x4*)(p1 + 128);
  f32x4 b1 = *(const f32x4*)(p1 + 132);
  float hv[8];
#pragma unroll
  for (int j = 0; j < 4; ++j) {
    float g1 = a0[j] * sA[cb + j] + sB[cb + j];
    float g2 = b0[j] * sA[cb + 128 + j] + sB[cb + 128 + j];
    hv[j] = g1 / (1.f + __expf(-g2));
    float g1b = a1[j] * sA[cb + 4 + j] + sB[cb + 4 + j];
    float g2b = b1[j] * sA[cb + 132 + j] + sB[cb + 132 + j];
    hv[4 + j] = g1b / (1.f + __expf(-g2b));
  }
  if (VARIANT >= 1) {
    f16x8 hpv = *(const f16x8*)(hp + (size_t)r * 128 + cb);
#pragma unroll
    for (int j = 0; j < 8; ++j) hv[j] = (hv[j] + (float)hpv[j]) * SQH_C;
  }
  f16x8 hov;
#pragma unroll
  for (int j = 0; j < 8; ++j) hov[j] = (f16)hv[j];
  *(f16x8*)(ho + (size_t)r * 128 + cb) = hov;
  if (VARIANT == 2) {
    if (cb < 64) {
      float* dp = dout + (size_t)r * 64 + cb;
#pragma unroll
      for (int j = 0; j < 8; ++j) {
        float rl = fmaxf(hv[j], 0.f);
        dp[j] = first ? rl : (dp[j] + rl);
      }
    }
  }
}

// ---------------- mask: ghost-BN(att) -> sparsemax -> masks, prior, entropy ----------------
__launch_bounds__(1024)
__global__ void mask_k(const float* __restrict__ pre, const float* __restrict__ vbst,
                       const float* __restrict__ ga, const float* __restrict__ ba,
                       const f16* __restrict__ prin, f16* __restrict__ prout,
                       float* __restrict__ mk, float* __restrict__ slpart, int step) {
  __shared__ float swsum[16];
  const int tid = threadIdx.x;
  const int wv = tid >> 6, ln = tid & 63;
  const int row = (blockIdx.x << 4) + wv;  // 1 wave per row
  const int c0 = ln << 2;                  // 4 features per lane
  const int vb = row >> 10;
  float z[4], pr[4];
  if (step == 0) {
    // h_a == 0 -> ghost_bn(0) = b ; prior = 1
#pragma unroll
    for (int j = 0; j < 4; ++j) { pr[j] = 1.f; z[j] = ba[c0 + j]; }
  } else {
    f32x4 pv = *(const f32x4*)(pre + (size_t)row * 256 + c0);
    f16x4 pp = *(const f16x4*)(prin + (size_t)row * 256 + c0);
    f32x4 st0 = *(const f32x4*)(vbst + ((size_t)(vb << 8) + c0) * 2);
    f32x4 st1 = *(const f32x4*)(vbst + ((size_t)(vb << 8) + c0) * 2 + 4);
    float s1[4] = {st0[0], st0[2], st1[0], st1[2]};
    float s2[4] = {st0[1], st0[3], st1[1], st1[3]};
#pragma unroll
    for (int j = 0; j < 4; ++j) {
      float mu = s1[j] * (1.f / VBS_C);
      float var = s2[j] * (1.f / VBS_C) - mu * mu;
      float rs = rsqrtf(var + EPS_C);
      float a = (pv[j] - mu) * rs * ga[c0 + j] + ba[c0 + j];
      pr[j] = (float)pp[j];
      z[j] = pr[j] * a;
    }
  }
  // sparsemax via bisection on f(tau) = sum(relu(z - tau)) - 1 (exact root of sort formulation)
  float m = fmaxf(fmaxf(z[0], z[1]), fmaxf(z[2], z[3]));
#pragma unroll
  for (int d = 1; d < 64; d <<= 1) m = fmaxf(m, __shfl_xor(m, d));
  float lo = m - 1.f, hi = m;
  for (int it = 0; it < 24; ++it) {
    float tau = 0.5f * (lo + hi);
    float s = fmaxf(z[0] - tau, 0.f) + fmaxf(z[1] - tau, 0.f) +
              fmaxf(z[2] - tau, 0.f) + fmaxf(z[3] - tau, 0.f);
#pragma unroll
    for (int d = 1; d < 64; d <<= 1) s += __shfl_xor(s, d);
    if (s > 1.f) lo = tau; else hi = tau;
  }
  const float tau = 0.5f * (lo + hi);
  float* mrow = mk + (size_t)row * 256 + c0;  // masks region is only 4B-aligned: scalar stores
  float ent = 0.f;
  float Mv[4];
#pragma unroll
  for (int j = 0; j < 4; ++j) {
    float M = fmaxf(z[j] - tau, 0.f);
    Mv[j] = M;
    mrow[j] = M;
    ent -= M * __logf(M + 1e-15f);
  }
  f16x4 pn;
#pragma unroll
  for (int j = 0; j < 4; ++j) pn[j] = (f16)(pr[j] * (GAMMA_C - Mv[j]));
  *(f16x4*)(prout + (size_t)row * 256 + c0) = pn;
#pragma unroll
  for (int d = 1; d < 64; d <<= 1) ent += __shfl_xor(ent, d);
  if (ln == 0) swsum[wv] = ent;
  __syncthreads();
  if (tid == 0) {
    float t = 0.f;
#pragma unroll
    for (int i = 0; i < 16; ++i) t += swsum[i];
    slpart[blockIdx.x] = t * SL_SCALE;
  }
}

__global__ void sl_reduce(const float* __restrict__ part, float* __restrict__ out, int n) {
  __shared__ float sm[256];
  float s = 0.f;
  for (int i = threadIdx.x; i < n; i += 256) s += part[i];
  sm[threadIdx.x] = s;
  __syncthreads();
  for (int d = 128; d > 0; d >>= 1) {
    if ((int)threadIdx.x < d) sm[threadIdx.x] += sm[threadIdx.x + d];
    __syncthreads();
  }
  if (threadIdx.x == 0) out[0] = sm[0];
}

// ---------------- host ----------------
extern "C" void kernel_launch(void* const* d_in, const int* in_sizes, int n_in,
                              void* d_out, int out_size, void* d_ws, size_t ws_size,
                              hipStream_t stream) {
  (void)in_sizes; (void)n_in; (void)out_size; (void)ws_size;
  const float* x    = (const float*)d_in[0];
  const float* bn0g = (const float*)d_in[1];
  const float* bn0b = (const float*)d_in[2];
  const float* Wsh0 = (const float*)d_in[3];
  const float* gsh0 = (const float*)d_in[4];
  const float* bsh0 = (const float*)d_in[5];
  const float* Wsh1 = (const float*)d_in[6];
  const float* gsh1 = (const float*)d_in[7];
  const float* bsh1 = (const float*)d_in[8];
  const float* Wstep = (const float*)d_in[9];
  const float* gstep = (const float*)d_in[10];
  const float* bstep = (const float*)d_in[11];
  const float* Watt = (const float*)d_in[12];
  const float* gatt = (const float*)d_in[13];
  const float* batt = (const float*)d_in[14];

  float* dout = (float*)d_out;
  float* slo = dout + (size_t)B_ROWS * 64;
  float* masks = slo + 1;

  char* ws = (char*)d_ws;
  size_t off = 0;
  auto carve = [&](size_t bytes) -> char* {
    char* p = ws + off;
    off += (bytes + 255) & ~(size_t)255;
    return p;
  };
  f16* wt_att  = (f16*)carve((size_t)3 * 256 * 64 * 2);
  f16* wt_sh0  = (f16*)carve((size_t)256 * 256 * 2);
  f16* wt_sh1  = (f16*)carve((size_t)256 * 128 * 2);
  f16* wt_step = (f16*)carve((size_t)6 * 256 * 128 * 2);
  float* bn0sum = (float*)carve(512 * 4);
  float* bnA    = (float*)carve(256 * 4);
  float* bnB    = (float*)carve(256 * 4);
  float* vbst   = (float*)carve((size_t)NVB * 256 * 2 * 4);
  float* slpart = (float*)carve((size_t)3 * 16384 * 4);
  f16* prior    = (f16*)carve((size_t)B_ROWS * 256 * 2);
  float* pre    = (float*)carve((size_t)B_ROWS * 256 * 4);
  f16* h0       = (f16*)carve((size_t)B_ROWS * 128 * 2);
  f16* h1       = (f16*)carve((size_t)B_ROWS * 128 * 2);

  // prep
  hipMemsetAsync(bn0sum, 0, 512 * 4, stream);
  bn0_accum<<<2048, 256, 0, stream>>>(x, bn0sum);
  bn0_final<<<1, 256, 0, stream>>>(bn0sum, bn0g, bn0b, bnA, bnB);
  for (int s = 0; s < 3; ++s)
    wprep<<<64, 256, 0, stream>>>(Watt + (size_t)s * 64 * 256, wt_att + (size_t)s * 256 * 64, 64);
  wprep<<<256, 256, 0, stream>>>(Wsh0, wt_sh0, 256);
  wprep<<<128, 256, 0, stream>>>(Wsh1, wt_sh1, 128);
  for (int i = 0; i < 6; ++i)
    wprep<<<128, 256, 0, stream>>>(Wstep + (size_t)i * 128 * 256, wt_step + (size_t)i * 256 * 128, 128);

  const size_t STB = (size_t)NVB * 256 * 2 * 4;
  for (int s = 0; s < 3; ++s) {
    float* mk = masks + (size_t)s * B_ROWS * 256;
    if (s > 0) {
      hipMemsetAsync(vbst, 0, STB, stream);
      gemm_k<64, 0><<<4096, 256, 0, stream>>>(h1 + 64, 128, nullptr, nullptr, nullptr, nullptr,
                                              wt_att + (size_t)s * 256 * 64, pre, vbst);
    }
    mask_k<<<16384, 1024, 0, stream>>>(pre, vbst, gatt + s * 256, batt + s * 256,
                                       prior, prior, mk, slpart + s * 16384, s);
    hipMemsetAsync(vbst, 0, STB, stream);
    gemm_k<256, 1><<<4096, 256, 0, stream>>>(nullptr, 0, mk, x, bnA, bnB, wt_sh0, pre, vbst);
    glu_k<0><<<16384, 256, 0, stream>>>(pre, vbst, gsh0, bsh0, nullptr, h0, nullptr, 0);
    hipMemsetAsync(vbst, 0, STB, stream);
    gemm_k<128, 0><<<4096, 256, 0, stream>>>(h0, 128, nullptr, nullptr, nullptr, nullptr, wt_sh1, pre, vbst);
    glu_k<1><<<16384, 256, 0, stream>>>(pre, vbst, gsh1, bsh1, h0, h1, nullptr, 0);
    hipMemsetAsync(vbst, 0, STB, stream);
    gemm_k<128, 0><<<4096, 256, 0, stream>>>(h1, 128, nullptr, nullptr, nullptr, nullptr,
                                             wt_step + (size_t)(s * 2 + 0) * 256 * 128, pre, vbst);
    glu_k<1><<<16384, 256, 0, stream>>>(pre, vbst, gstep + (s * 2 + 0) * 256, bstep + (s * 2 + 0) * 256,
                                        h1, h0, nullptr, 0);
    hipMemsetAsync(vbst, 0, STB, stream);
    gemm_k<128, 0><<<4096, 256, 0, stream>>>(h0, 128, nullptr, nullptr, nullptr, nullptr,
                                             wt_step + (size_t)(s * 2 + 1) * 256 * 128, pre, vbst);
    glu_k<2><<<16384, 256, 0, stream>>>(pre, vbst, gstep + (s * 2 + 1) * 256, bstep + (s * 2 + 1) * 256,
                                        h0, h1, dout, s == 0);
  }
  sl_reduce<<<1, 256, 0, stream>>>(slpart, slo, 3 * 16384);
}

// Round 3
// 1902.254 us; speedup vs baseline: 2.2103x; 2.2103x over previous
//
#include <hip/hip_runtime.h>
#include <math.h>

#define B_ROWS 262144
#define GAMMA_C 1.3f
#define EPS_C 1e-5f
#define SQH_C 0.70710678118654752440f
#define SL_SCALE (1.0f/201326592.0f)   // 1/(3*B*256)

typedef _Float16 f16;
typedef f16 f16x8 __attribute__((ext_vector_type(8)));
typedef float f32x4 __attribute__((ext_vector_type(4)));

// XOR-swizzle: 16B slot index XORed with low row bits (RB = row bytes)
template<int RB>
__device__ __forceinline__ unsigned swz(int row, int kb) {
  constexpr int M = (RB/16 - 1) < 31 ? (RB/16 - 1) : 31;
  return (unsigned)(row * RB + (kb ^ ((row & M) << 4)));
}

// ---------------- bn0: full-batch stats ----------------
__global__ void bn0_accum(const float* __restrict__ x, float* __restrict__ sums) {
  const int col = threadIdx.x;
  const size_t r0 = (size_t)blockIdx.x * 128;
  float s1 = 0.f, s2 = 0.f;
  for (int i = 0; i < 128; ++i) {
    float v = x[(r0 + i) * 256 + col];
    s1 += v; s2 += v * v;
  }
  atomicAdd(&sums[col * 2], s1);
  atomicAdd(&sums[col * 2 + 1], s2);
}

__global__ void bn0_final(const float* __restrict__ sums, const float* __restrict__ g,
                          const float* __restrict__ b, float* __restrict__ bnA,
                          float* __restrict__ bnB) {
  int c = threadIdx.x;
  float mu = sums[c * 2] * (1.f / B_ROWS);
  float var = sums[c * 2 + 1] * (1.f / B_ROWS) - mu * mu;
  float a = rsqrtf(var + EPS_C) * g[c];
  bnA[c] = a;
  bnB[c] = b[c] - mu * a;
}

// ---------------- weight prep: f32 [K][256] -> f16 [256][K] ----------------
__global__ void wprep(const float* __restrict__ src, f16* __restrict__ dst, int K) {
  int idx = blockIdx.x * 256 + threadIdx.x;
  int n = idx / K, k = idx - n * K;
  dst[idx] = (f16)src[(size_t)k * 256 + n];
}

// ---------------- m0: step-0 mask row (identical for all rows) ----------------
__global__ void m0_kernel(const float* __restrict__ ba, float* __restrict__ m0v,
                          float* __restrict__ prior1v, float* __restrict__ slpart) {
  const int l = threadIdx.x;       // 64 threads
  const int c0 = l << 2;
  float z[4];
#pragma unroll
  for (int j = 0; j < 4; ++j) z[j] = ba[c0 + j];
  float m = fmaxf(fmaxf(z[0], z[1]), fmaxf(z[2], z[3]));
#pragma unroll
  for (int d = 1; d < 64; d <<= 1) m = fmaxf(m, __shfl_xor(m, d));
  float lo = m - 1.f, hi = m;
  for (int it = 0; it < 24; ++it) {
    float tau = 0.5f * (lo + hi);
    float s = fmaxf(z[0] - tau, 0.f) + fmaxf(z[1] - tau, 0.f) +
              fmaxf(z[2] - tau, 0.f) + fmaxf(z[3] - tau, 0.f);
#pragma unroll
    for (int d = 1; d < 64; d <<= 1) s += __shfl_xor(s, d);
    if (s > 1.f) lo = tau; else hi = tau;
  }
  const float tau = 0.5f * (lo + hi);
  float ent = 0.f;
#pragma unroll
  for (int j = 0; j < 4; ++j) {
    float M = fmaxf(z[j] - tau, 0.f);
    m0v[c0 + j] = M;
    prior1v[c0 + j] = GAMMA_C - M;
    ent -= M * __logf(M + 1e-15f);
  }
#pragma unroll
  for (int d = 1; d < 64; d <<= 1) ent += __shfl_xor(ent, d);
  if (l == 0) slpart[512] = ent * (262144.f * SL_SCALE);
}

// ---------------- step-0 masks broadcast + Mx = m0 * x_bn ----------------
__global__ void mx0_kernel(const float* __restrict__ x, const float* __restrict__ m0v,
                           const float* __restrict__ bnA, const float* __restrict__ bnB,
                           float* __restrict__ mk, f16* __restrict__ Mx) {
  __shared__ float sm[256], sa[256], sb[256];
  const int tid = threadIdx.x;
  sm[tid] = m0v[tid]; sa[tid] = bnA[tid]; sb[tid] = bnB[tid];
  __syncthreads();
  const size_t r = (size_t)blockIdx.x * 8 + (tid >> 5);
  const int c0 = (tid & 31) << 3;
  const float* xp = x + r * 256 + c0;
  f32x4 x0 = *(const f32x4*)xp;
  f32x4 x1 = *(const f32x4*)(xp + 4);
  float* mp = mk + r * 256 + c0;   // masks region only 4B-aligned: scalar stores
  f16x8 mxv;
#pragma unroll
  for (int j = 0; j < 4; ++j) {
    mp[j] = sm[c0 + j];
    mp[4 + j] = sm[c0 + 4 + j];
    mxv[j] = (f16)(sm[c0 + j] * (x0[j] * sa[c0 + j] + sb[c0 + j]));
    mxv[4 + j] = (f16)(sm[c0 + 4 + j] * (x1[j] * sa[c0 + 4 + j] + sb[c0 + 4 + j]));
  }
  *(f16x8*)(Mx + r * 256 + c0) = mxv;
}

// ---------------- fused two-pass GEMM + ghost-BN + GLU (one WG per VB) ----------------
// KDIM: 256 (A=Mx) or 128 (A=h-prev). VARIANT: 0 plain GLU; 1 +residual; 2 +residual+dout.
template <int KDIM, int VARIANT>
__launch_bounds__(1024)
__global__ void fused_glu(const f16* __restrict__ Ag, const f16* __restrict__ Wt,
                          const float* __restrict__ gv, const float* __restrict__ bv,
                          f16* __restrict__ ho, float* __restrict__ dout,
                          int first, int writeH) {
  constexpr int RC  = (KDIM == 128) ? 64 : 32;   // rows per chunk
  constexpr int NCH = 1024 / RC;
  constexpr int NRT = RC / 32;                    // row-tiles per wave
  constexpr int KS  = KDIM / 32;
  constexpr int RB  = KDIM * 2;                   // LDS row bytes
  constexpr int TPR = KDIM / 8;                   // staging threads per row
  __shared__ f16 sW[256 * KDIM];
  __shared__ f16 sA[RC * KDIM];
  __shared__ float sS1[256], sS2[256], sAf[256], sBf[256];
  char* sWc = (char*)sW;
  char* sAc = (char*)sA;
  const int tid = threadIdx.x;
  const int r0 = blockIdx.x << 10;
  const int w = tid >> 6, l = tid & 63, lc = l & 15, lg = l >> 4;
  const int mw = w >> 3, nw = w & 7;
  if (tid < 256) { sS1[tid] = 0.f; sS2[tid] = 0.f; }
  // stage full W (n-major, k contig) into LDS, swizzled
#pragma unroll
  for (int it = 0; it < KDIM / 32; ++it) {
    int flat = it * 1024 + tid;
    int rw = flat / TPR, kc = flat % TPR;
    *(f16x8*)(sWc + swz<RB>(rw, kc * 16)) = *(const f16x8*)(Wt + rw * KDIM + kc * 8);
  }
  const int arow = tid / TPR, akc = tid % TPR;
  const f16* aB = Ag + (size_t)(r0 + arow) * KDIM + akc * 8;

  for (int pass = 0; pass < 2; ++pass) {
    float st1[2] = {0.f, 0.f}, st2[2] = {0.f, 0.f};
    f16x8 pv = *(const f16x8*)(aB);
    for (int ch = 0; ch < NCH; ++ch) {
      __syncthreads();
      *(f16x8*)(sAc + swz<RB>(arow, akc * 16)) = pv;
      __syncthreads();
      if (ch + 1 < NCH) pv = *(const f16x8*)(aB + (size_t)(ch + 1) * RC * KDIM);
      f32x4 acc[NRT][2];
#pragma unroll
      for (int i = 0; i < NRT; ++i) {
        acc[i][0] = {0.f, 0.f, 0.f, 0.f};
        acc[i][1] = {0.f, 0.f, 0.f, 0.f};
      }
#pragma unroll
      for (int ks = 0; ks < KS; ++ks) {
        f16x8 af[NRT];
#pragma unroll
        for (int i = 0; i < NRT; ++i)
          af[i] = *(const f16x8*)(sAc + swz<RB>(mw * 16 * NRT + i * 16 + lc, ks * 64 + lg * 16));
        f16x8 b0 = *(const f16x8*)(sWc + swz<RB>(nw * 16 + lc, ks * 64 + lg * 16));
        f16x8 b1 = *(const f16x8*)(sWc + swz<RB>((nw + 8) * 16 + lc, ks * 64 + lg * 16));
#pragma unroll
        for (int i = 0; i < NRT; ++i) {
          acc[i][0] = __builtin_amdgcn_mfma_f32_16x16x32_f16(af[i], b0, acc[i][0], 0, 0, 0);
          acc[i][1] = __builtin_amdgcn_mfma_f32_16x16x32_f16(af[i], b1, acc[i][1], 0, 0, 0);
        }
      }
      if (pass == 0) {
#pragma unroll
        for (int t = 0; t < 2; ++t) {
          float s1 = 0.f, s2 = 0.f;
#pragma unroll
          for (int i = 0; i < NRT; ++i)
#pragma unroll
            for (int j = 0; j < 4; ++j) { float v = acc[i][t][j]; s1 += v; s2 += v * v; }
          st1[t] += s1; st2[t] += s2;
        }
      } else {
        const int c1 = nw * 16 + lc;
        const float a1 = sAf[c1], o1 = sBf[c1], a2 = sAf[c1 + 128], o2 = sBf[c1 + 128];
#pragma unroll
        for (int i = 0; i < NRT; ++i) {
          const int rloc = mw * 16 * NRT + i * 16 + lg * 4;
          const size_t rg = (size_t)(r0 + ch * RC) + rloc;
#pragma unroll
          for (int j = 0; j < 4; ++j) {
            float g1 = acc[i][0][j] * a1 + o1;
            float g2 = acc[i][1][j] * a2 + o2;
            float hv = g1 / (1.f + __expf(-g2));
            if (VARIANT >= 1) {
              f16 hp = *(const f16*)(sAc + swz<RB>(rloc + j, c1 * 2));
              hv = (hv + (float)hp) * SQH_C;
            }
            if (VARIANT < 2 || writeH) ho[(rg + j) * 128 + c1] = (f16)hv;
            if (VARIANT == 2 && nw < 4) {
              float rl = fmaxf(hv, 0.f);
              float* dp = dout + (rg + j) * 64 + c1;
              *dp = first ? rl : (*dp + rl);
            }
          }
        }
      }
    }
    if (pass == 0) {
#pragma unroll
      for (int t = 0; t < 2; ++t) {
        float v1 = st1[t], v2 = st2[t];
        v1 += __shfl_xor(v1, 16); v2 += __shfl_xor(v2, 16);
        v1 += __shfl_xor(v1, 32); v2 += __shfl_xor(v2, 32);
        if (l < 16) {
          int c = (nw + t * 8) * 16 + lc;
          atomicAdd(&sS1[c], v1);
          atomicAdd(&sS2[c], v2);
        }
      }
      __syncthreads();
      if (tid < 256) {
        float mu = sS1[tid] * (1.f / 1024.f);
        float var = sS2[tid] * (1.f / 1024.f) - mu * mu;
        float a = rsqrtf(var + EPS_C) * gv[tid];
        sAf[tid] = a;
        sBf[tid] = bv[tid] - mu * a;
      }
    }
  }
}

// ---------------- fused attention GEMM + ghost-BN + sparsemax + mask products ----------------
// SMODE 1: prior = broadcast vector, writes prior buffer. SMODE 2: prior = buffer, no write.
template <int SMODE>
__launch_bounds__(512)
__global__ void attmask(const f16* __restrict__ h1, const f16* __restrict__ Wt,
                        const float* __restrict__ ga, const float* __restrict__ ba,
                        const float* __restrict__ bnA, const float* __restrict__ bnB,
                        const float* __restrict__ prior1v, const f16* __restrict__ prin,
                        f16* __restrict__ prout, const float* __restrict__ x,
                        float* __restrict__ mk, f16* __restrict__ Mx,
                        float* __restrict__ slpart) {
  __shared__ f16 sW[256 * 64];
  __shared__ f16 sA[128 * 64];
  __shared__ float sS1[256], sS2[256], sAf[256], sBf[256], sbA[256], sbB[256], spv[256];
  __shared__ float sEnt[8];
  char* sWc = (char*)sW;
  char* sAc = (char*)sA;
  const int tid = threadIdx.x;
  const int vb = blockIdx.x;
  const int r0 = vb << 10;
  const int w = tid >> 6, l = tid & 63, lc = l & 15, lg = l >> 4;
  if (tid < 256) {
    sS1[tid] = 0.f; sS2[tid] = 0.f;
    sbA[tid] = bnA[tid]; sbB[tid] = bnB[tid];
    if (SMODE == 1) spv[tid] = prior1v[tid];
  }
#pragma unroll
  for (int it = 0; it < 4; ++it) {
    int flat = it * 512 + tid;
    int rw = flat >> 3, kc = flat & 7;
    *(f16x8*)(sWc + swz<128>(rw, kc * 16)) = *(const f16x8*)(Wt + rw * 64 + kc * 8);
  }
  const int arow = tid >> 3, akc = tid & 7;
  const f16* aB = h1 + (size_t)(r0 + arow) * 128 + 64 + akc * 8;
  float ent = 0.f;

  for (int pass = 0; pass < 2; ++pass) {
    float st1[16], st2[16];
#pragma unroll
    for (int t = 0; t < 16; ++t) { st1[t] = 0.f; st2[t] = 0.f; }
    f16x8 pv0 = *(const f16x8*)(aB);
    f16x8 pv1 = *(const f16x8*)(aB + (size_t)64 * 128);
    for (int ch = 0; ch < 8; ++ch) {
      __syncthreads();
      *(f16x8*)(sAc + swz<128>(arow, akc * 16)) = pv0;
      *(f16x8*)(sAc + swz<128>(arow + 64, akc * 16)) = pv1;
      __syncthreads();
      if (ch + 1 < 8) {
        pv0 = *(const f16x8*)(aB + (size_t)(ch + 1) * 128 * 128);
        pv1 = *(const f16x8*)(aB + (size_t)((ch + 1) * 128 + 64) * 128);
      }
      f16x8 af0 = *(const f16x8*)(sAc + swz<128>(w * 16 + lc, lg * 16));
      f16x8 af1 = *(const f16x8*)(sAc + swz<128>(w * 16 + lc, 64 + lg * 16));
      const int rb = r0 + ch * 128 + w * 16;
      f32x4 z[16];
#pragma unroll
      for (int t = 0; t < 16; ++t) {
        f16x8 b0 = *(const f16x8*)(sWc + swz<128>(t * 16 + lc, lg * 16));
        f16x8 b1 = *(const f16x8*)(sWc + swz<128>(t * 16 + lc, 64 + lg * 16));
        f32x4 acc = {0.f, 0.f, 0.f, 0.f};
        acc = __builtin_amdgcn_mfma_f32_16x16x32_f16(af0, b0, acc, 0, 0, 0);
        acc = __builtin_amdgcn_mfma_f32_16x16x32_f16(af1, b1, acc, 0, 0, 0);
        if (pass == 0) {
          float s1 = 0.f, s2 = 0.f;
#pragma unroll
          for (int j = 0; j < 4; ++j) { float v = acc[j]; s1 += v; s2 += v * v; }
          st1[t] += s1; st2[t] += s2;
        } else {
          const int c = t * 16 + lc;
          const float a = sAf[c], bb = sBf[c];
#pragma unroll
          for (int j = 0; j < 4; ++j) {
            float pr;
            if (SMODE == 1) pr = spv[c];
            else pr = (float)prin[(size_t)(rb + lg * 4 + j) * 256 + c];
            z[t][j] = (acc[j] * a + bb) * pr;
          }
        }
      }
      if (pass == 1) {
        // in-register sparsemax for rows rb + lg*4 + {0..3}
        f32x4 mj, lo, hi;
#pragma unroll
        for (int j = 0; j < 4; ++j) {
          float m = z[0][j];
#pragma unroll
          for (int t = 1; t < 16; ++t) m = fmaxf(m, z[t][j]);
          mj[j] = m;
        }
#pragma unroll
        for (int d = 1; d < 16; d <<= 1)
#pragma unroll
          for (int j = 0; j < 4; ++j) mj[j] = fmaxf(mj[j], __shfl_xor(mj[j], d));
#pragma unroll
        for (int j = 0; j < 4; ++j) { lo[j] = mj[j] - 1.f; hi[j] = mj[j]; }
        for (int itb = 0; itb < 20; ++itb) {
          f32x4 tau, sv;
#pragma unroll
          for (int j = 0; j < 4; ++j) { tau[j] = 0.5f * (lo[j] + hi[j]); sv[j] = 0.f; }
#pragma unroll
          for (int t = 0; t < 16; ++t)
#pragma unroll
            for (int j = 0; j < 4; ++j) sv[j] += fmaxf(z[t][j] - tau[j], 0.f);
#pragma unroll
          for (int d = 1; d < 16; d <<= 1)
#pragma unroll
            for (int j = 0; j < 4; ++j) sv[j] += __shfl_xor(sv[j], d);
#pragma unroll
          for (int j = 0; j < 4; ++j) { if (sv[j] > 1.f) lo[j] = tau[j]; else hi[j] = tau[j]; }
        }
        f32x4 tau;
#pragma unroll
        for (int j = 0; j < 4; ++j) tau[j] = 0.5f * (lo[j] + hi[j]);
#pragma unroll
        for (int t = 0; t < 16; ++t) {
          const int c = t * 16 + lc;
#pragma unroll
          for (int j = 0; j < 4; ++j) {
            const size_t r = (size_t)(rb + lg * 4 + j);
            float Mv = fmaxf(z[t][j] - tau[j], 0.f);
            mk[r * 256 + c] = Mv;
            ent -= Mv * __logf(Mv + 1e-15f);
            float xb = x[r * 256 + c] * sbA[c] + sbB[c];
            Mx[r * 256 + c] = (f16)(Mv * xb);
            if (SMODE == 1) prout[r * 256 + c] = (f16)(spv[c] * (GAMMA_C - Mv));
          }
        }
      }
    }
    if (pass == 0) {
#pragma unroll
      for (int t = 0; t < 16; ++t) {
        float v1 = st1[t], v2 = st2[t];
        v1 += __shfl_xor(v1, 16); v2 += __shfl_xor(v2, 16);
        v1 += __shfl_xor(v1, 32); v2 += __shfl_xor(v2, 32);
        if (l < 16) {
          atomicAdd(&sS1[t * 16 + lc], v1);
          atomicAdd(&sS2[t * 16 + lc], v2);
        }
      }
      __syncthreads();
      if (tid < 256) {
        float mu = sS1[tid] * (1.f / 1024.f);
        float var = sS2[tid] * (1.f / 1024.f) - mu * mu;
        float a = rsqrtf(var + EPS_C) * ga[tid];
        sAf[tid] = a;
        sBf[tid] = ba[tid] - mu * a;
      }
    }
  }
#pragma unroll
  for (int d = 1; d < 64; d <<= 1) ent += __shfl_xor(ent, d);
  if (l == 0) sEnt[w] = ent;
  __syncthreads();
  if (tid == 0) {
    float t = 0.f;
#pragma unroll
    for (int i = 0; i < 8; ++i) t += sEnt[i];
    slpart[(SMODE - 1) * 256 + vb] = t * SL_SCALE;
  }
}

__global__ void sl_reduce(const float* __restrict__ part, float* __restrict__ out, int n) {
  __shared__ float sm[256];
  float s = 0.f;
  for (int i = threadIdx.x; i < n; i += 256) s += part[i];
  sm[threadIdx.x] = s;
  __syncthreads();
  for (int d = 128; d > 0; d >>= 1) {
    if ((int)threadIdx.x < d) sm[threadIdx.x] += sm[threadIdx.x + d];
    __syncthreads();
  }
  if (threadIdx.x == 0) out[0] = sm[0];
}

// ---------------- host ----------------
extern "C" void kernel_launch(void* const* d_in, const int* in_sizes, int n_in,
                              void* d_out, int out_size, void* d_ws, size_t ws_size,
                              hipStream_t stream) {
  (void)in_sizes; (void)n_in; (void)out_size; (void)ws_size;
  const float* x    = (const float*)d_in[0];
  const float* bn0g = (const float*)d_in[1];
  const float* bn0b = (const float*)d_in[2];
  const float* Wsh0 = (const float*)d_in[3];
  const float* gsh0 = (const float*)d_in[4];
  const float* bsh0 = (const float*)d_in[5];
  const float* Wsh1 = (const float*)d_in[6];
  const float* gsh1 = (const float*)d_in[7];
  const float* bsh1 = (const float*)d_in[8];
  const float* Wstep = (const float*)d_in[9];
  const float* gstep = (const float*)d_in[10];
  const float* bstep = (const float*)d_in[11];
  const float* Watt = (const float*)d_in[12];
  const float* gatt = (const float*)d_in[13];
  const float* batt = (const float*)d_in[14];

  float* dout = (float*)d_out;
  float* slo = dout + (size_t)B_ROWS * 64;
  float* masks = slo + 1;

  char* ws = (char*)d_ws;
  size_t off = 0;
  auto carve = [&](size_t bytes) -> char* {
    char* p = ws + off;
    off += (bytes + 255) & ~(size_t)255;
    return p;
  };
  f16* wt_att   = (f16*)carve((size_t)3 * 256 * 64 * 2);
  f16* wt_sh0   = (f16*)carve((size_t)256 * 256 * 2);
  f16* wt_sh1   = (f16*)carve((size_t)256 * 128 * 2);
  f16* wt_step  = (f16*)carve((size_t)6 * 256 * 128 * 2);
  float* bn0sum = (float*)carve(512 * 4);
  float* bnA    = (float*)carve(256 * 4);
  float* bnB    = (float*)carve(256 * 4);
  float* m0v    = (float*)carve(256 * 4);
  float* prior1v= (float*)carve(256 * 4);
  float* slpart = (float*)carve(513 * 4);
  f16* prior    = (f16*)carve((size_t)B_ROWS * 256 * 2);
  f16* Mx       = (f16*)carve((size_t)B_ROWS * 256 * 2);
  f16* h0       = (f16*)carve((size_t)B_ROWS * 128 * 2);
  f16* h1       = (f16*)carve((size_t)B_ROWS * 128 * 2);

  // prep
  hipMemsetAsync(bn0sum, 0, 512 * 4, stream);
  bn0_accum<<<2048, 256, 0, stream>>>(x, bn0sum);
  bn0_final<<<1, 256, 0, stream>>>(bn0sum, bn0g, bn0b, bnA, bnB);
  for (int s = 1; s < 3; ++s)
    wprep<<<64, 256, 0, stream>>>(Watt + (size_t)s * 64 * 256, wt_att + (size_t)s * 256 * 64, 64);
  wprep<<<256, 256, 0, stream>>>(Wsh0, wt_sh0, 256);
  wprep<<<128, 256, 0, stream>>>(Wsh1, wt_sh1, 128);
  for (int i = 0; i < 6; ++i)
    wprep<<<128, 256, 0, stream>>>(Wstep + (size_t)i * 128 * 256, wt_step + (size_t)i * 256 * 128, 128);
  m0_kernel<<<1, 64, 0, stream>>>(batt, m0v, prior1v, slpart);
  mx0_kernel<<<B_ROWS / 8, 256, 0, stream>>>(x, m0v, bnA, bnB, masks, Mx);

  for (int s = 0; s < 3; ++s) {
    if (s == 1)
      attmask<1><<<256, 512, 0, stream>>>(h1, wt_att + (size_t)1 * 256 * 64,
                                          gatt + 256, batt + 256, bnA, bnB,
                                          prior1v, nullptr, prior, x,
                                          masks + (size_t)1 * B_ROWS * 256, Mx, slpart);
    else if (s == 2)
      attmask<2><<<256, 512, 0, stream>>>(h1, wt_att + (size_t)2 * 256 * 64,
                                          gatt + 512, batt + 512, bnA, bnB,
                                          nullptr, prior, nullptr, x,
                                          masks + (size_t)2 * B_ROWS * 256, Mx, slpart);
    fused_glu<256, 0><<<256, 1024, 0, stream>>>(Mx, wt_sh0, gsh0, bsh0, h0, nullptr, 0, 1);
    fused_glu<128, 1><<<256, 1024, 0, stream>>>(h0, wt_sh1, gsh1, bsh1, h1, nullptr, 0, 1);
    fused_glu<128, 1><<<256, 1024, 0, stream>>>(h1, wt_step + (size_t)(s * 2 + 0) * 256 * 128,
                                                gstep + (s * 2 + 0) * 256, bstep + (s * 2 + 0) * 256,
                                                h0, nullptr, 0, 1);
    fused_glu<128, 2><<<256, 1024, 0, stream>>>(h0, wt_step + (size_t)(s * 2 + 1) * 256 * 128,
                                                gstep + (s * 2 + 1) * 256, bstep + (s * 2 + 1) * 256,
                                                h1, dout, s == 0, s < 2);
  }
  sl_reduce<<<1, 256, 0, stream>>>(slpart, slo, 513);
}